// Round 1
// 63.459 us; speedup vs baseline: 1.0040x; 1.0040x over previous
//
#include <hip/hip_runtime.h>

// CurveGraphic2d: 16 cubic Beziers rendered onto 256x256 canvases (fp32).
// Per batch: 64 arc-length-uniform samples; per pixel:
// min distance to samples -> (d/w + eps)^aa -> clip(1 - ., 0, 1).
//
// Dtype: fp32 in / fp32 out.
//
// Structure: proven LDS-based pipeline for phases 1-3 (NO wave shuffles —
// both rounds that used __shfl scan/binary-search produced blank canvases).
// Phase 4 (this round): 2 rows per wave, 4 px per lane per row.
//   - dy/dy^2 computed once per sample and amortized over 8 px (row B's
//     dy is row A's dy - 1.0f: one sub, not a fresh sub+mul).
//   - per-(px,sample) cost drops 3.5 -> 3.0 VALU ops; ds_read count per
//     px halves. Grid 1024 -> 512 blocks (8 rows/block).
// This is a floor probe: kernel-attributable time is ~4-5 us of the 63.7 us
// metric (top rocprof dispatches are the harness's 40.5 us / 268 MB poison
// fills at 83% HBM peak). If dur_us is unmoved, the bench is harness-floored.

#define EPSILON 1e-6f
#define NS 64

__device__ __forceinline__ void bezier4(const float cy[4], const float cx[4],
                                        float t, float& ry, float& rx) {
    float s = 1.0f - t;
    float ay0 = s * cy[0] + t * cy[1];
    float ay1 = s * cy[1] + t * cy[2];
    float ay2 = s * cy[2] + t * cy[3];
    float by0 = s * ay0 + t * ay1;
    float by1 = s * ay1 + t * ay2;
    ry = s * by0 + t * by1;
    float ax0 = s * cx[0] + t * cx[1];
    float ax1 = s * cx[1] + t * cx[2];
    float ax2 = s * cx[2] + t * cx[3];
    float bx0 = s * ax0 + t * ax1;
    float bx1 = s * ax1 + t * ax2;
    rx = s * bx0 + t * bx1;
}

__global__ __launch_bounds__(256) void curve_kernel(
    const float* __restrict__ inputs,   // [16,4,2] (y,x) in [0,1]
    const float* __restrict__ widths,   // [16]
    const float* __restrict__ aas,      // [16]
    float* __restrict__ out)            // [16,256,256]
{
    __shared__ float s_y0[NS], s_x0[NS];   // pts0 at uniform t
    __shared__ float s_seg[NS];            // segment lengths
    __shared__ float s_cum[NS];            // cumulative arc length
    __shared__ float s_total;
    __shared__ float2 s_pts[NS];           // final sample points (y,x)

    const int b       = blockIdx.x >> 5;         // 32 blocks per batch
    const int rowbase = (blockIdx.x & 31) << 3;  // 8 rows per block
    const int tid     = threadIdx.x;

    // ---- phase 1: pts0 = bezier(linspace(0,1,64)) ----
    float cy[4], cx[4];
    if (tid < NS) {
        #pragma unroll
        for (int i = 0; i < 4; ++i) {
            cy[i] = inputs[b * 8 + 2 * i + 0] * 256.0f;
            cx[i] = inputs[b * 8 + 2 * i + 1] * 256.0f;
        }
        const float t0 = (float)tid / 63.0f;
        float py, px;
        bezier4(cy, cx, t0, py, px);
        s_y0[tid] = py;
        s_x0[tid] = px;
    }
    __syncthreads();

    // ---- phase 2a: parallel segment lengths ----
    if (tid < NS - 1) {
        float dy = s_y0[tid + 1] - s_y0[tid];
        float dx = s_x0[tid + 1] - s_x0[tid];
        s_seg[tid] = sqrtf(dy * dy + dx * dx);
    }
    __syncthreads();

    // ---- phase 2b: serial cumsum, register chain (matches jnp.cumsum order)
    if (tid == 0) {
        float c = 0.0f;
        s_cum[0] = 0.0f;
        #pragma unroll
        for (int l = 1; l < NS; ++l) {      // 63 pipelined LDS reads,
            c += s_seg[l - 1];              // dependent chain = adds only
            s_cum[l] = c;
        }
        s_total = c;
    }
    __syncthreads();

    // ---- phase 3: t_arc = np.interp(t0, u, ts0), resample ----
    if (tid < NS) {
        const float t0   = (float)tid / 63.0f;
        const float invT = 1.0f / (s_total + EPSILON);
        // largest j with u[j] <= t0, u[j] = cum[j]*invT (u[0]=0, increasing)
        int lo = 0, hi = 63;
        #pragma unroll
        for (int it = 0; it < 6; ++it) {
            int mid = (lo + hi + 1) >> 1;
            if (s_cum[mid] * invT <= t0) lo = mid; else hi = mid - 1;
        }
        float t_arc;
        if (lo >= 63) {
            t_arc = 1.0f;                     // query beyond u[-1] -> ts0[-1]
        } else {
            float uj    = s_cum[lo] * invT;
            float uj1   = s_cum[lo + 1] * invT;
            float denom = uj1 - uj;
            float tsj   = (float)lo / 63.0f;
            t_arc = (denom > 0.0f)
                  ? tsj + (t0 - uj) / denom * (1.0f / 63.0f)
                  : tsj;
        }
        float sy, sx;
        bezier4(cy, cx, t_arc, sy, sx);
        s_pts[tid] = make_float2(sy, sx);
    }
    __syncthreads();

    // ---- phase 4: render TWO rows per wave, 4 px per lane per row ----
    const float w    = widths[b];
    const float aa   = aas[b];
    const float invw = 1.0f / w;

    const int wave = tid >> 6;
    const int lane = tid & 63;
    const int rowA = rowbase + (wave << 1);   // even; rowB = rowA + 1
    const float pyA = (float)rowA;
    const float px0 = (float)(lane << 2);

    float a0 = 1e30f, a1 = 1e30f, a2 = 1e30f, a3 = 1e30f;  // row A mins
    float b0 = 1e30f, b1 = 1e30f, b2 = 1e30f, b3 = 1e30f;  // row B mins
    #pragma unroll 16
    for (int i = 0; i < NS; ++i) {
        float2 sp  = s_pts[i];                // wave-uniform broadcast read
        float dyA  = sp.x - pyA;
        float dyB  = dyA - 1.0f;              // row B = row A + 1
        float y2A  = dyA * dyA;
        float y2B  = dyB * dyB;
        float dx   = sp.y - px0;
        float d;
        d = fmaf(dx, dx, y2A); a0 = fminf(a0, d);
        d = fmaf(dx, dx, y2B); b0 = fminf(b0, d); dx -= 1.0f;
        d = fmaf(dx, dx, y2A); a1 = fminf(a1, d);
        d = fmaf(dx, dx, y2B); b1 = fminf(b1, d); dx -= 1.0f;
        d = fmaf(dx, dx, y2A); a2 = fminf(a2, d);
        d = fmaf(dx, dx, y2B); b2 = fminf(b2, d); dx -= 1.0f;
        d = fmaf(dx, dx, y2A); a3 = fminf(a3, d);
        d = fmaf(dx, dx, y2B); b3 = fminf(b3, d);
    }

    float msA[4] = { a0, a1, a2, a3 };
    float msB[4] = { b0, b1, b2, b3 };
    float vA[4], vB[4];
    #pragma unroll
    for (int k = 0; k < 4; ++k) {
        float mdA = sqrtf(msA[k]);              // sqrt(min d^2) == min d
        float cA  = mdA * invw + EPSILON;
        float vvA = 1.0f - exp2f(aa * log2f(cA)); // c^aa, c >= 1e-6 > 0
        vA[k] = fminf(fmaxf(vvA, 0.0f), 1.0f);
        float mdB = sqrtf(msB[k]);
        float cB  = mdB * invw + EPSILON;
        float vvB = 1.0f - exp2f(aa * log2f(cB));
        vB[k] = fminf(fmaxf(vvB, 0.0f), 1.0f);
    }

    const int baseA = (b << 16) | (rowA << 8) | (lane << 2);        // element idx
    const int baseB = baseA + 256;                                  // rowA + 1
    reinterpret_cast<float4*>(out)[baseA >> 2] =
        make_float4(vA[0], vA[1], vA[2], vA[3]);
    reinterpret_cast<float4*>(out)[baseB >> 2] =
        make_float4(vB[0], vB[1], vB[2], vB[3]);
}

extern "C" void kernel_launch(void* const* d_in, const int* in_sizes, int n_in,
                              void* d_out, int out_size, void* d_ws, size_t ws_size,
                              hipStream_t stream) {
    const float* inp = (const float*)d_in[0];
    const float* wid = (const float*)d_in[1];
    const float* aaf = (const float*)d_in[2];
    float* out = (float*)d_out;

    dim3 grid(16 * 32);   // 16 batches x 32 blocks (8 rows each)
    dim3 block(256);
    hipLaunchKernelGGL(curve_kernel, grid, block, 0, stream,
                       inp, wid, aaf, out);
}